// Round 1
// baseline (1246.365 us; speedup 1.0000x reference)
//
#include <hip/hip_runtime.h>
#include <math.h>

typedef float2 cplx;

#define TPB 256
#define KTAYLOR 12
#define IN_DIM 4000
#define NREPS 4

// Swizzled LDS index: element (row, col) stored at row*64 + (col ^ row).
// Makes column-strided reads (fixed col, varying row) bank-conflict-free.
__device__ __forceinline__ int swz(int row, int col) { return (row << 6) | (col ^ row); }

// Pauli index p (base-4 digits, MSB digit = qubit 0 = row bit 5) -> masks.
// digit: I=00 X=01 Y=10 Z=11 (hi,lo bits). x-bit = hi^lo, z-bit = hi.
__device__ __forceinline__ void pauli_masks(int p, int& xm, int& zm) {
    xm = 0; zm = 0;
    #pragma unroll
    for (int k = 0; k < 6; k++) {
        int lo = (p >> (2 * k)) & 1;
        int hi = (p >> (2 * k + 1)) & 1;
        zm |= hi << k;
        xm |= (hi ^ lo) << k;
    }
}

// coefficient v, masks -> D[m][z] = v * (-i)^popcount(m&z)
__device__ __forceinline__ cplx pauli_phase(float v, int xm, int zm) {
    int ny = __popc(xm & zm) & 3;
    if (ny == 0) return make_float2(v, 0.f);
    if (ny == 1) return make_float2(0.f, -v);
    if (ny == 2) return make_float2(-v, 0.f);
    return make_float2(0.f, v);
}

// Precondition: Wbuf[swz(m,z)] = D[m][z] (coeff * (-i)^|Y|), sumsq = per-thread
// partial of sum coeff^2. Postcondition: Wbuf[swz(i,j)] = exp(-iH)[i][j].
// Abuf is scratch (holds scaled A during Taylor; first 1KB used for reduction).
__device__ void expm_core(cplx* Abuf, cplx* Wbuf, int t, float sumsq)
{
    // ---- block reduction of sum(coeff^2) -> Frobenius norm bound ----
    float* red = (float*)Abuf;
    red[t] = sumsq;
    __syncthreads();
    for (int off = 128; off >= 1; off >>= 1) {
        if (t < off) red[t] += red[t + off];
        __syncthreads();
    }
    float fro = sqrtf(64.0f * red[0]);   // ||H||_F = sqrt(DIM * sum c_p^2) >= ||H||_2
    __syncthreads();
    int s = 0; float nn = fro;
    while (nn > 1.0f && s < 30) { nn *= 0.5f; s++; }
    float scale = exp2f((float)(-s));

    // ---- WHT over z within each row m: h_m[i] = sum_z D[m][z] (-1)^pc(i&z) ----
    for (int st = 0; st < 6; st++) {
        int len = 1 << st;
        for (int n = 0; n < 8; n++) {
            int q  = t + TPB * n;       // 2048 butterflies/stage
            int m  = q >> 5;
            int bf = q & 31;
            int lo = bf & (len - 1);
            int hi = bf >> st;
            int z0 = (hi << (st + 1)) | lo;
            int z1 = z0 | len;
            cplx a = Wbuf[swz(m, z0)];
            cplx b = Wbuf[swz(m, z1)];
            Wbuf[swz(m, z0)] = make_float2(a.x + b.x, a.y + b.y);
            Wbuf[swz(m, z1)] = make_float2(a.x - b.x, a.y - b.y);
        }
        __syncthreads();
    }

    // ---- scatter: A[i][i^m] = -i * h_m[i] * 2^-s ----
    for (int n = 0; n < 16; n++) {
        int idx = t + TPB * n;
        int m = idx >> 6, i = idx & 63;
        cplx h = Wbuf[swz(m, i)];
        Abuf[swz(i, i ^ m)] = make_float2(h.y * scale, -h.x * scale);
    }
    __syncthreads();

    // ---- Taylor: U = I + A + A^2/2! + ... + A^K/K!  (u in registers) ----
    const int i = t >> 2, jb = t & 3;   // thread covers row i, cols jb+4*jj
    cplx u[16], c[16];
    #pragma unroll
    for (int jj = 0; jj < 16; jj++) {
        int j = jb + (jj << 2);
        cplx a = Abuf[swz(i, j)];
        u[jj] = make_float2((i == j ? 1.0f : 0.0f) + a.x, a.y);
    }
    const cplx* Tcur = Abuf;            // T_1 = A
    for (int k = 2; k <= KTAYLOR; k++) {
        #pragma unroll
        for (int jj = 0; jj < 16; jj++) c[jj] = make_float2(0.f, 0.f);
        for (int kk = 0; kk < 64; kk++) {
            cplx a = Abuf[swz(i, kk)];
            #pragma unroll
            for (int jj = 0; jj < 16; jj++) {
                cplx b = Tcur[swz(kk, jb + (jj << 2))];
                c[jj].x = fmaf(a.x, b.x, fmaf(-a.y, b.y, c[jj].x));
                c[jj].y = fmaf(a.x, b.y, fmaf( a.y, b.x, c[jj].y));
            }
        }
        float rk = 1.0f / (float)k;
        __syncthreads();                 // all reads of Tcur done
        #pragma unroll
        for (int jj = 0; jj < 16; jj++) {
            c[jj].x *= rk; c[jj].y *= rk;
            Wbuf[swz(i, jb + (jj << 2))] = c[jj];   // T_k (in place)
            u[jj].x += c[jj].x; u[jj].y += c[jj].y;
        }
        __syncthreads();
        Tcur = Wbuf;
    }
    // U -> Wbuf
    #pragma unroll
    for (int jj = 0; jj < 16; jj++) Wbuf[swz(i, jb + (jj << 2))] = u[jj];
    __syncthreads();

    // ---- s squarings, in place with reg staging ----
    for (int q = 0; q < s; q++) {
        #pragma unroll
        for (int jj = 0; jj < 16; jj++) c[jj] = make_float2(0.f, 0.f);
        for (int kk = 0; kk < 64; kk++) {
            cplx a = Wbuf[swz(i, kk)];
            #pragma unroll
            for (int jj = 0; jj < 16; jj++) {
                cplx b = Wbuf[swz(kk, jb + (jj << 2))];
                c[jj].x = fmaf(a.x, b.x, fmaf(-a.y, b.y, c[jj].x));
                c[jj].y = fmaf(a.x, b.y, fmaf( a.y, b.x, c[jj].y));
            }
        }
        __syncthreads();
        #pragma unroll
        for (int jj = 0; jj < 16; jj++) Wbuf[swz(i, jb + (jj << 2))] = c[jj];
        __syncthreads();
    }
}

// Parameter unitaries: Up[r] = exp(-i sum_p w[r,p-1] P_p), p = 1..4095
__global__ __launch_bounds__(TPB) void up_kernel(const float* __restrict__ w,
                                                 cplx* __restrict__ up)
{
    __shared__ cplx Abuf[4096];
    __shared__ cplx Wbuf[4096];
    int t = threadIdx.x;
    int r = blockIdx.x;
    float sumsq = 0.f;
    for (int n = 0; n < 16; n++) {
        int p = t + TPB * n;
        float v = (p == 0) ? 0.f : w[r * 4095 + p - 1];
        sumsq += v * v;
        int xm, zm; pauli_masks(p, xm, zm);
        Wbuf[swz(xm, zm)] = pauli_phase(v, xm, zm);
    }
    __syncthreads();
    expm_core(Abuf, Wbuf, t, sumsq);
    for (int n = 0; n < 16; n++) {
        int idx = t + TPB * n;
        int i = idx >> 6, j = idx & 63;
        up[r * 4096 + idx] = Wbuf[swz(i, j)];   // un-swizzled row-major
    }
}

// Per-sample: build Ud = exp(-iHd), run circuit, emit probs + bias
__global__ __launch_bounds__(TPB) void circuit_kernel(const float* __restrict__ x,
                                                      const cplx* __restrict__ up,
                                                      const float* __restrict__ bias,
                                                      float* __restrict__ out)
{
    __shared__ cplx Abuf[4096];
    __shared__ cplx Wbuf[4096];
    int t = threadIdx.x;
    int b = blockIdx.x;
    float sumsq = 0.f;
    for (int n = 0; n < 16; n++) {
        int p = t + TPB * n;
        float v = (p < IN_DIM) ? x[b * IN_DIM + p] : 0.f;
        sumsq += v * v;
        int xm, zm; pauli_masks(p, xm, zm);
        Wbuf[swz(xm, zm)] = pauli_phase(v, xm, zm);
    }
    __syncthreads();
    expm_core(Abuf, Wbuf, t, sumsq);   // Ud now in Wbuf (swizzled)

    // ---- circuit: psi = (Up[3] Ud ... Up[0] Ud) e0 ; Abuf reused for psi ----
    cplx* psi0 = Abuf;
    cplx* psi1 = Abuf + 64;
    if (t < 64) psi0[t] = make_float2(t == 0 ? 1.f : 0.f, 0.f);
    __syncthreads();
    for (int r = 0; r < NREPS; r++) {
        if (t < 64) {
            cplx acc = make_float2(0.f, 0.f);
            for (int j = 0; j < 64; j++) {
                cplx m = Wbuf[swz(t, j)];
                cplx p = psi0[j];
                acc.x = fmaf(m.x, p.x, fmaf(-m.y, p.y, acc.x));
                acc.y = fmaf(m.x, p.y, fmaf( m.y, p.x, acc.y));
            }
            psi1[t] = acc;
        }
        __syncthreads();
        if (t < 64) {
            const cplx* urow = up + r * 4096 + t * 64;
            cplx acc = make_float2(0.f, 0.f);
            for (int j = 0; j < 64; j++) {
                cplx m = urow[j];
                cplx p = psi1[j];
                acc.x = fmaf(m.x, p.x, fmaf(-m.y, p.y, acc.x));
                acc.y = fmaf(m.x, p.y, fmaf( m.y, p.x, acc.y));
            }
            psi0[t] = acc;
        }
        __syncthreads();
    }
    if (t < 64) {
        cplx pv = psi0[t];
        out[b * 64 + t] = fmaf(pv.x, pv.x, fmaf(pv.y, pv.y, bias[t]));
    }
}

extern "C" void kernel_launch(void* const* d_in, const int* in_sizes, int n_in,
                              void* d_out, int out_size, void* d_ws, size_t ws_size,
                              hipStream_t stream)
{
    const float* x    = (const float*)d_in[0];
    const float* w    = (const float*)d_in[1];
    const float* bias = (const float*)d_in[2];
    float* out = (float*)d_out;
    cplx* up   = (cplx*)d_ws;               // 4 * 64*64 complex = 128 KB scratch

    int B = in_sizes[0] / IN_DIM;           // 512

    hipLaunchKernelGGL(up_kernel,      dim3(NREPS), dim3(TPB), 0, stream, w, up);
    hipLaunchKernelGGL(circuit_kernel, dim3(B),     dim3(TPB), 0, stream, x, up, bias, out);
}

// Round 2
// 635.646 us; speedup vs baseline: 1.9608x; 1.9608x over previous
//
#include <hip/hip_runtime.h>
#include <math.h>

typedef float2 cplx;

#define TPB 256
#define KTAYLOR 12
#define IN_DIM 4000
#define NREPS 4

// ---------------------------------------------------------------------------
// Layouts:
//   X: plain row-major, element (m, c) at X[m*64 + c].            (32 KB)
//   Y: transposed evolving operand, swizzled: logical YT[m][r] = T[r][m]
//      stored at Y[m*64 + (r ^ S(m))], S(m) = ((m>>2)&7)<<1.      (32 KB)
//      S is even -> aligned 16B pairs are preserved (possibly relocated),
//      never internally permuted, so float4 LDS ops need no lane fixup.
// Thread tiling: t in [0,256): ri = t>>4, ci = t&15; thread owns the 4x4
// C-tile rows 4ri..4ri+3, cols 4ci..4ci+3.
// ---------------------------------------------------------------------------

// C-tile = sum_kk  YT[kk][4ri..+3] (x) B[kk][4ci..+3]
// bFromYT=false: B row read from X (plain).  bFromYT=true: B = evolving matrix
// itself, read transposed from Y (squaring step: C = U*U).
__device__ __forceinline__ void mm_step(const cplx* __restrict__ X,
                                        const cplx* __restrict__ Y,
                                        int ri, int ci, bool bFromYT,
                                        float* __restrict__ cre,
                                        float* __restrict__ cim)
{
    const int sb = (ci & 7) << 1;       // S(4ci+dc), independent of dc
    for (int kk = 0; kk < 64; kk++) {
        int sa = ((kk >> 2) & 7) << 1;
        const float4* Yrow = (const float4*)(Y + (kk << 6));
        int pa = (((ri << 2) ^ sa) >> 1);
        float4 a01 = Yrow[pa];          // T[4ri+0][kk], T[4ri+1][kk]
        float4 a23 = Yrow[pa ^ 1];      // T[4ri+2][kk], T[4ri+3][kk]

        float4 b01, b23;
        if (bFromYT) {
            int pb = kk ^ sb;
            const cplx* base = Y + (ci << 8) + pb;   // rows 4ci+dc, col kk
            cplx b0 = base[0];
            cplx b1 = base[64];
            cplx b2 = base[128];
            cplx b3 = base[192];
            b01 = make_float4(b0.x, b0.y, b1.x, b1.y);
            b23 = make_float4(b2.x, b2.y, b3.x, b3.y);
        } else {
            const float4* Xrow = (const float4*)(X + (kk << 6));
            b01 = Xrow[ci << 1];
            b23 = Xrow[(ci << 1) | 1];
        }

        float ar0 = a01.x, ai0 = a01.y, ar1 = a01.z, ai1 = a01.w;
        float ar2 = a23.x, ai2 = a23.y, ar3 = a23.z, ai3 = a23.w;
        float br0 = b01.x, bi0 = b01.y, br1 = b01.z, bi1 = b01.w;
        float br2 = b23.x, bi2 = b23.y, br3 = b23.z, bi3 = b23.w;

        #define CF(id, AR, AI, BR, BI)                                    \
            cre[id] = fmaf(AR, BR, fmaf(-(AI), (BI), cre[id]));           \
            cim[id] = fmaf(AR, BI, fmaf((AI), (BR), cim[id]));
        CF( 0, ar0, ai0, br0, bi0)  CF( 1, ar0, ai0, br1, bi1)
        CF( 2, ar0, ai0, br2, bi2)  CF( 3, ar0, ai0, br3, bi3)
        CF( 4, ar1, ai1, br0, bi0)  CF( 5, ar1, ai1, br1, bi1)
        CF( 6, ar1, ai1, br2, bi2)  CF( 7, ar1, ai1, br3, bi3)
        CF( 8, ar2, ai2, br0, bi0)  CF( 9, ar2, ai2, br1, bi1)
        CF(10, ar2, ai2, br2, bi2)  CF(11, ar2, ai2, br3, bi3)
        CF(12, ar3, ai3, br0, bi0)  CF(13, ar3, ai3, br1, bi1)
        CF(14, ar3, ai3, br2, bi2)  CF(15, ar3, ai3, br3, bi3)
        #undef CF
    }
}

// Write the 4x4 tile into Y in transposed+swizzled layout.
__device__ __forceinline__ void writeYT(cplx* __restrict__ Y, int ri, int ci,
                                        const float* __restrict__ cre,
                                        const float* __restrict__ cim)
{
    const int sb = (ci & 7) << 1;
    const int p = (((ri << 2) ^ sb) >> 1);
    #pragma unroll
    for (int dc = 0; dc < 4; dc++) {
        float4* Yrow = (float4*)(Y + (((ci << 2) + dc) << 6));
        Yrow[p]     = make_float4(cre[dc], cim[dc], cre[4 + dc], cim[4 + dc]);
        Yrow[p ^ 1] = make_float4(cre[8 + dc], cim[8 + dc], cre[12 + dc], cim[12 + dc]);
    }
}

// Precondition: X[m*64+z] = D[m][z] = c_{(m,z)} * (-i)^popc(m&z); sumsq =
// per-thread partial of sum c^2.  Postcondition: X[i*64+j] = exp(-iH)[i][j]
// (plain row-major).  Y is scratch.
__device__ void expm_core(cplx* X, cplx* Y, int t, float sumsq)
{
    const int ri = t >> 4, ci = t & 15;

    // ---- reduce sum(c^2) -> Frobenius bound ||H||_2 <= sqrt(64*sum c^2) ----
    float* red = (float*)Y;
    red[t] = sumsq;
    __syncthreads();
    for (int off = 128; off >= 1; off >>= 1) {
        if (t < off) red[t] += red[t + off];
        __syncthreads();
    }
    float fro = sqrtf(64.0f * red[0]);
    __syncthreads();
    int s = 0; float nn = fro;
    while (nn > 2.0f && s < 30) { nn *= 0.5f; s++; }   // theta = 2
    float scale = exp2f((float)(-s));

    // ---- WHT over z within each row m: X[m][i] <- h_m(i) ----
    for (int st = 0; st < 6; st++) {
        int len = 1 << st;
        #pragma unroll
        for (int n = 0; n < 8; n++) {
            int q = t + TPB * n;
            int m = q >> 5, bf = q & 31;
            int lo = bf & (len - 1), hi = bf >> st;
            int z0 = (hi << (st + 1)) | lo;
            int z1 = z0 | len;
            cplx a = X[(m << 6) + z0], b = X[(m << 6) + z1];
            X[(m << 6) + z0] = make_float2(a.x + b.x, a.y + b.y);
            X[(m << 6) + z1] = make_float2(a.x - b.x, a.y - b.y);
        }
        __syncthreads();
    }

    // ---- scatter: A[i][i^m] = -i*h_m(i)*2^-s;  X <- A, Y <- A^T(swz) ----
    cplx hv[16];
    #pragma unroll
    for (int n = 0; n < 16; n++) hv[n] = X[t + TPB * n];
    __syncthreads();
    #pragma unroll
    for (int n = 0; n < 16; n++) {
        int idx = t + TPB * n;
        int m = idx >> 6, i = idx & 63;
        cplx av = make_float2(hv[n].y * scale, -hv[n].x * scale);
        int r = i, c = i ^ m;
        X[(r << 6) + c] = av;
        Y[(c << 6) + (r ^ (((c >> 2) & 7) << 1))] = av;
    }
    __syncthreads();

    // ---- u = I + A (tile in registers) ----
    float ure[16], uim[16];
    #pragma unroll
    for (int dr = 0; dr < 4; dr++) {
        const float4* Xrow = (const float4*)(X + (((ri << 2) + dr) << 6));
        float4 x01 = Xrow[ci << 1], x23 = Xrow[(ci << 1) | 1];
        int r = (ri << 2) + dr, c0 = ci << 2;
        ure[dr * 4 + 0] = x01.x + (r == c0     ? 1.f : 0.f);  uim[dr * 4 + 0] = x01.y;
        ure[dr * 4 + 1] = x01.z + (r == c0 + 1 ? 1.f : 0.f);  uim[dr * 4 + 1] = x01.w;
        ure[dr * 4 + 2] = x23.x + (r == c0 + 2 ? 1.f : 0.f);  uim[dr * 4 + 2] = x23.y;
        ure[dr * 4 + 3] = x23.z + (r == c0 + 3 ? 1.f : 0.f);  uim[dr * 4 + 3] = x23.w;
    }

    // ---- Taylor: T_k = T_{k-1} * A (A commutes with its powers) ----
    float fct = 1.0f;
    for (int k = 2; k <= KTAYLOR; k++) {
        float cre[16], cim[16];
        #pragma unroll
        for (int id = 0; id < 16; id++) { cre[id] = 0.f; cim[id] = 0.f; }
        mm_step(X, Y, ri, ci, false, cre, cim);
        __syncthreads();                     // all reads of Y (T_{k-1}) done
        writeYT(Y, ri, ci, cre, cim);        // Y <- T_k = A^k
        fct /= (float)k;
        #pragma unroll
        for (int id = 0; id < 16; id++) {
            ure[id] = fmaf(cre[id], fct, ure[id]);
            uim[id] = fmaf(cim[id], fct, uim[id]);
        }
        __syncthreads();
    }
    // Y <- U (transposed layout)
    writeYT(Y, ri, ci, ure, uim);
    __syncthreads();

    // ---- s squarings: U <- U*U, right operand read transposed from Y ----
    for (int q = 0; q < s; q++) {
        float cre[16], cim[16];
        #pragma unroll
        for (int id = 0; id < 16; id++) { cre[id] = 0.f; cim[id] = 0.f; }
        mm_step(X, Y, ri, ci, true, cre, cim);
        __syncthreads();
        writeYT(Y, ri, ci, cre, cim);
        __syncthreads();
    }

    // ---- final transpose: X[r][c] = YT[c][r] = U[r][c] (plain layout) ----
    {
        const int sb = (ci & 7) << 1;
        #pragma unroll
        for (int dr = 0; dr < 4; dr++) {
            int r = (ri << 2) + dr;
            int pp = r ^ sb;
            cplx v0 = Y[(((ci << 2) + 0) << 6) + pp];
            cplx v1 = Y[(((ci << 2) + 1) << 6) + pp];
            cplx v2 = Y[(((ci << 2) + 2) << 6) + pp];
            cplx v3 = Y[(((ci << 2) + 3) << 6) + pp];
            float4* Xrow = (float4*)(X + (r << 6));
            Xrow[ci << 1]       = make_float4(v0.x, v0.y, v1.x, v1.y);
            Xrow[(ci << 1) | 1] = make_float4(v2.x, v2.y, v3.x, v3.y);
        }
    }
    __syncthreads();
}

// Pauli index p -> (xmask, zmask)
__device__ __forceinline__ void pauli_masks(int p, int& xm, int& zm) {
    xm = 0; zm = 0;
    #pragma unroll
    for (int k = 0; k < 6; k++) {
        int lo = (p >> (2 * k)) & 1;
        int hi = (p >> (2 * k + 1)) & 1;
        zm |= hi << k;
        xm |= (hi ^ lo) << k;
    }
}

__device__ __forceinline__ cplx pauli_phase(float v, int xm, int zm) {
    int ny = __popc(xm & zm) & 3;
    if (ny == 0) return make_float2(v, 0.f);
    if (ny == 1) return make_float2(0.f, -v);
    if (ny == 2) return make_float2(-v, 0.f);
    return make_float2(0.f, v);
}

// acc = M[i][:] . pin  with per-lane chunk rotation to break same-bank rows
__device__ __forceinline__ cplx matvec_row(const cplx* __restrict__ M,
                                           const cplx* __restrict__ pin, int i)
{
    float ax = 0.f, ay = 0.f;
    const float4* Mr = (const float4*)(M + (i << 6));
    #pragma unroll
    for (int mm = 0; mm < 16; mm++) {
        int ch = (mm + (i & 15)) & 15;
        float4 m01 = Mr[ch << 1], m23 = Mr[(ch << 1) | 1];
        const cplx* p = pin + (ch << 2);
        cplx p0 = p[0], p1 = p[1], p2 = p[2], p3 = p[3];
        ax = fmaf(m01.x, p0.x, fmaf(-m01.y, p0.y, ax));
        ay = fmaf(m01.x, p0.y, fmaf( m01.y, p0.x, ay));
        ax = fmaf(m01.z, p1.x, fmaf(-m01.w, p1.y, ax));
        ay = fmaf(m01.z, p1.y, fmaf( m01.w, p1.x, ay));
        ax = fmaf(m23.x, p2.x, fmaf(-m23.y, p2.y, ax));
        ay = fmaf(m23.x, p2.y, fmaf( m23.y, p2.x, ay));
        ax = fmaf(m23.z, p3.x, fmaf(-m23.w, p3.y, ax));
        ay = fmaf(m23.z, p3.y, fmaf( m23.w, p3.x, ay));
    }
    return make_float2(ax, ay);
}

// ---- parameter unitaries: Up[r] = exp(-i sum_p w[r,p-1] P_p) ----
__global__ __launch_bounds__(TPB) void up_kernel(const float* __restrict__ w,
                                                 cplx* __restrict__ up)
{
    __shared__ float4 Xs4[2048];
    __shared__ float4 Ys4[2048];
    cplx* X = (cplx*)Xs4;
    cplx* Y = (cplx*)Ys4;
    int t = threadIdx.x;
    int r = blockIdx.x;
    float sumsq = 0.f;
    #pragma unroll
    for (int n = 0; n < 16; n++) {
        int p = t + TPB * n;
        float v = (p == 0) ? 0.f : w[r * 4095 + p - 1];
        sumsq += v * v;
        int xm, zm; pauli_masks(p, xm, zm);
        X[(xm << 6) + zm] = pauli_phase(v, xm, zm);
    }
    __syncthreads();
    expm_core(X, Y, t, sumsq);
    float4* dst = (float4*)(up + (r << 12));
    const float4* src = (const float4*)X;
    #pragma unroll
    for (int n = 0; n < 8; n++) dst[n * TPB + t] = src[n * TPB + t];
}

// ---- per-sample: Ud = exp(-iHd), circuit, probs + bias ----
__global__ __launch_bounds__(TPB) void circuit_kernel(const float* __restrict__ x,
                                                      const cplx* __restrict__ up,
                                                      const float* __restrict__ bias,
                                                      float* __restrict__ out)
{
    __shared__ float4 Xs4[2048];
    __shared__ float4 Ys4[2048];
    __shared__ cplx psiA[64], psiB[64];
    cplx* X = (cplx*)Xs4;
    cplx* Y = (cplx*)Ys4;
    int t = threadIdx.x;
    int b = blockIdx.x;
    float sumsq = 0.f;
    #pragma unroll
    for (int n = 0; n < 16; n++) {
        int p = t + TPB * n;
        float v = (p < IN_DIM) ? x[b * IN_DIM + p] : 0.f;
        sumsq += v * v;
        int xm, zm; pauli_masks(p, xm, zm);
        X[(xm << 6) + zm] = pauli_phase(v, xm, zm);
    }
    __syncthreads();
    expm_core(X, Y, t, sumsq);      // X = Ud row-major; Y now free

    if (t < 64) psiA[t] = make_float2(t == 0 ? 1.f : 0.f, 0.f);
    __syncthreads();

    for (int r = 0; r < NREPS; r++) {
        // stage Up[r] into Y (plain row-major), coalesced
        const float4* src = (const float4*)(up + (r << 12));
        float4* dstY = (float4*)Y;
        #pragma unroll
        for (int n = 0; n < 8; n++) dstY[n * TPB + t] = src[n * TPB + t];
        __syncthreads();
        if (t < 64) psiB[t] = matvec_row(X, psiA, t);
        __syncthreads();
        if (t < 64) psiA[t] = matvec_row(Y, psiB, t);
        __syncthreads();
    }
    if (t < 64) {
        cplx pv = psiA[t];
        out[(b << 6) + t] = fmaf(pv.x, pv.x, fmaf(pv.y, pv.y, bias[t]));
    }
}

extern "C" void kernel_launch(void* const* d_in, const int* in_sizes, int n_in,
                              void* d_out, int out_size, void* d_ws, size_t ws_size,
                              hipStream_t stream)
{
    const float* x    = (const float*)d_in[0];
    const float* w    = (const float*)d_in[1];
    const float* bias = (const float*)d_in[2];
    float* out = (float*)d_out;
    cplx* up   = (cplx*)d_ws;               // 4 * 4096 cplx = 128 KB scratch

    int B = in_sizes[0] / IN_DIM;           // 512

    hipLaunchKernelGGL(up_kernel,      dim3(NREPS), dim3(TPB), 0, stream, w, up);
    hipLaunchKernelGGL(circuit_kernel, dim3(B),     dim3(TPB), 0, stream, x, up, bias, out);
}

// Round 3
// 571.469 us; speedup vs baseline: 2.1810x; 1.1123x over previous
//
#include <hip/hip_runtime.h>
#include <math.h>

typedef float2 cplx;

#define TPB 256
#define IN_DIM 4000
#define NREPS 4

// 1/k! coefficients
#define C3f  0.16666667f
#define C4f  0.041666668f
#define C5f  8.3333333e-3f
#define C6f  1.3888889e-3f
#define C7f  1.9841270e-4f
#define C8f  2.4801587e-5f
#define C9f  2.7557319e-6f
#define C10f 2.7557319e-7f
#define C11f 2.5052108e-8f
#define C12f 2.0876757e-9f

// ---------------------------------------------------------------------------
// X ("plain-swizzled"): logical element (r,c) at X[r*64 + (c ^ (((c>>4)&1)<<1))],
//   i.e. 16B chunk k of a row stored at physical chunk k ^ ((k>>3)&1).
//   The 16 even (resp. odd) chunks then cover every bank quad exactly twice
//   -> 2-way aliasing = free. Reader addresses are thread-constant.
// Y ("transposed-swizzled"): logical YT[m][r] = T[r][m] at Y[m*64 + (r ^ S(m))],
//   S(m) = ((m>>2)&7)<<1 (even -> preserves aligned 16B pairs).
// Thread tiling: ri = t>>4, ci = t&15; 4x4 tile rows 4ri.., cols 4ci.. .
// Tile register layout: v[dr*4+dc].
// ---------------------------------------------------------------------------

// C += T(from Y) * B;  B from X (plain-swizzled) or transposed from Y (squaring)
__device__ __forceinline__ void mm_step(const cplx* __restrict__ X,
                                        const cplx* __restrict__ Y,
                                        int ri, int ci, int c1, int c2, bool bFromYT,
                                        float* __restrict__ cre,
                                        float* __restrict__ cim)
{
    const int sb = (ci & 7) << 1;
    #pragma unroll 8
    for (int kk = 0; kk < 64; kk++) {
        int sa = ((kk >> 2) & 7) << 1;
        const float4* Yrow = (const float4*)(Y + (kk << 6));
        int pa = (((ri << 2) ^ sa) >> 1);
        float4 a01 = Yrow[pa];          // T[4ri+0][kk], T[4ri+1][kk]
        float4 a23 = Yrow[pa ^ 1];      // T[4ri+2][kk], T[4ri+3][kk]

        float4 b01, b23;
        if (bFromYT) {
            int pb = kk ^ sb;
            const cplx* base = Y + (ci << 8) + pb;   // rows 4ci+dc, col kk
            cplx b0 = base[0];
            cplx b1 = base[64];
            cplx b2 = base[128];
            cplx b3 = base[192];
            b01 = make_float4(b0.x, b0.y, b1.x, b1.y);
            b23 = make_float4(b2.x, b2.y, b3.x, b3.y);
        } else {
            const float4* Xrow = (const float4*)(X + (kk << 6));
            b01 = Xrow[c1];             // cols 4ci+0,1
            b23 = Xrow[c2];             // cols 4ci+2,3
        }

        float ar0 = a01.x, ai0 = a01.y, ar1 = a01.z, ai1 = a01.w;
        float ar2 = a23.x, ai2 = a23.y, ar3 = a23.z, ai3 = a23.w;
        float br0 = b01.x, bi0 = b01.y, br1 = b01.z, bi1 = b01.w;
        float br2 = b23.x, bi2 = b23.y, br3 = b23.z, bi3 = b23.w;

        #define CF(id, AR, AI, BR, BI)                                    \
            cre[id] = fmaf(AR, BR, fmaf(-(AI), (BI), cre[id]));           \
            cim[id] = fmaf(AR, BI, fmaf((AI), (BR), cim[id]));
        CF( 0, ar0, ai0, br0, bi0)  CF( 1, ar0, ai0, br1, bi1)
        CF( 2, ar0, ai0, br2, bi2)  CF( 3, ar0, ai0, br3, bi3)
        CF( 4, ar1, ai1, br0, bi0)  CF( 5, ar1, ai1, br1, bi1)
        CF( 6, ar1, ai1, br2, bi2)  CF( 7, ar1, ai1, br3, bi3)
        CF( 8, ar2, ai2, br0, bi0)  CF( 9, ar2, ai2, br1, bi1)
        CF(10, ar2, ai2, br2, bi2)  CF(11, ar2, ai2, br3, bi3)
        CF(12, ar3, ai3, br0, bi0)  CF(13, ar3, ai3, br1, bi1)
        CF(14, ar3, ai3, br2, bi2)  CF(15, ar3, ai3, br3, bi3)
        #undef CF
    }
}

// Write 4x4 tile into Y (transposed-swizzled)
__device__ __forceinline__ void writeYT(cplx* __restrict__ Y, int ri, int ci,
                                        const float* __restrict__ vre,
                                        const float* __restrict__ vim)
{
    const int sb = (ci & 7) << 1;
    const int p = (((ri << 2) ^ sb) >> 1);
    #pragma unroll
    for (int dc = 0; dc < 4; dc++) {
        float4* Yrow = (float4*)(Y + (((ci << 2) + dc) << 6));
        Yrow[p]     = make_float4(vre[dc], vim[dc], vre[4 + dc], vim[4 + dc]);
        Yrow[p ^ 1] = make_float4(vre[8 + dc], vim[8 + dc], vre[12 + dc], vim[12 + dc]);
    }
}

// Write 4x4 tile into X (plain-swizzled)
__device__ __forceinline__ void writeXtile(cplx* __restrict__ X, int ri, int c1, int c2,
                                           const float* __restrict__ vre,
                                           const float* __restrict__ vim)
{
    #pragma unroll
    for (int dr = 0; dr < 4; dr++) {
        float4* Xrow = (float4*)(X + (((ri << 2) + dr) << 6));
        Xrow[c1] = make_float4(vre[dr*4+0], vim[dr*4+0], vre[dr*4+1], vim[dr*4+1]);
        Xrow[c2] = make_float4(vre[dr*4+2], vim[dr*4+2], vre[dr*4+3], vim[dr*4+3]);
    }
}

// Precondition: X[m*64+z] (UNswizzled) = D[m][z] = c_{(m,z)} * (-i)^popc(m&z);
// sumsq = per-thread partial of sum c^2.
// Postcondition: X = exp(-iH) in plain-swizzled layout. Y scratch.
__device__ void expm_core(cplx* X, cplx* Y, int t, float sumsq)
{
    const int ri = t >> 4, ci = t & 15;
    const int xb = (ci >> 2) & 1;
    const int c1 = (ci << 1) + xb;
    const int c2 = (ci << 1) + 1 - xb;

    // ---- reduce sum(c^2) -> ||H||_2 <= ||H||_F = sqrt(64*sum c^2) ----
    float* red = (float*)Y;
    red[t] = sumsq;
    __syncthreads();
    for (int off = 128; off >= 1; off >>= 1) {
        if (t < off) red[t] += red[t + off];
        __syncthreads();
    }
    float fro = sqrtf(64.0f * red[0]);
    __syncthreads();
    int s = 0; float nn = fro;
    while (nn > 2.0f && s < 30) { nn *= 0.5f; s++; }   // theta = 2
    float scale = exp2f((float)(-s));

    // ---- WHT over z within each row m ----
    for (int st = 0; st < 6; st++) {
        int len = 1 << st;
        #pragma unroll
        for (int n = 0; n < 8; n++) {
            int q = t + TPB * n;
            int m = q >> 5, bf = q & 31;
            int lo = bf & (len - 1), hi = bf >> st;
            int z0 = (hi << (st + 1)) | lo;
            int z1 = z0 | len;
            cplx a = X[(m << 6) + z0], b = X[(m << 6) + z1];
            X[(m << 6) + z0] = make_float2(a.x + b.x, a.y + b.y);
            X[(m << 6) + z1] = make_float2(a.x - b.x, a.y - b.y);
        }
        __syncthreads();
    }

    // ---- scatter: A[i][i^m] = -i*h_m(i)*2^-s;  X <- A (swz), Y <- A^T (swz) ----
    cplx hv[16];
    #pragma unroll
    for (int n = 0; n < 16; n++) hv[n] = X[t + TPB * n];
    __syncthreads();
    #pragma unroll
    for (int n = 0; n < 16; n++) {
        int idx = t + TPB * n;
        int m = idx >> 6, i = idx & 63;
        cplx av = make_float2(hv[n].y * scale, -hv[n].x * scale);
        int r = i, c = i ^ m;
        X[(r << 6) + (c ^ (((c >> 4) & 1) << 1))] = av;
        Y[(c << 6) + (r ^ (((c >> 2) & 7) << 1))] = av;
    }
    __syncthreads();

    // ---- A tile into registers ----
    float are[16], aim[16];
    #pragma unroll
    for (int dr = 0; dr < 4; dr++) {
        const float4* Xrow = (const float4*)(X + (((ri << 2) + dr) << 6));
        float4 x01 = Xrow[c1], x23 = Xrow[c2];
        are[dr*4+0] = x01.x; aim[dr*4+0] = x01.y;
        are[dr*4+1] = x01.z; aim[dr*4+1] = x01.w;
        are[dr*4+2] = x23.x; aim[dr*4+2] = x23.y;
        are[dr*4+3] = x23.z; aim[dr*4+3] = x23.w;
    }

    float cre[16], cim[16];
    #define ZERO_C  _Pragma("unroll") for (int id = 0; id < 16; id++) { cre[id] = 0.f; cim[id] = 0.f; }
    const bool onDiag = (ri == ci);

    // ---- mm1: A2 = A*A ----
    ZERO_C
    mm_step(X, Y, ri, ci, c1, c2, false, cre, cim);
    __syncthreads();
    writeYT(Y, ri, ci, cre, cim);            // Y <- A2^T
    float a2re[16], a2im[16];
    #pragma unroll
    for (int id = 0; id < 16; id++) { a2re[id] = cre[id]; a2im[id] = cim[id]; }
    __syncthreads();

    // ---- mm2: A3 = A2*A ----
    ZERO_C
    mm_step(X, Y, ri, ci, c1, c2, false, cre, cim);
    __syncthreads();
    writeYT(Y, ri, ci, cre, cim);            // Y <- A3^T (stays for all Horner mms)
    // Q3 = c9 I + c10 A + c11 A2 + c12 A3  -> X
    {
        float qre[16], qim[16];
        #pragma unroll
        for (int id = 0; id < 16; id++) {
            qre[id] = fmaf(C10f, are[id], fmaf(C11f, a2re[id], C12f * cre[id]));
            qim[id] = fmaf(C10f, aim[id], fmaf(C11f, a2im[id], C12f * cim[id]));
        }
        if (onDiag) { qre[0] += C9f; qre[5] += C9f; qre[10] += C9f; qre[15] += C9f; }
        writeXtile(X, ri, c1, c2, qre, qim);
    }
    __syncthreads();

    // ---- mm3: M3 = A3*Q3 ;  Q2 = c6 I + c7 A + c8 A2 + M3 -> X ----
    ZERO_C
    mm_step(X, Y, ri, ci, c1, c2, false, cre, cim);
    __syncthreads();
    {
        float qre[16], qim[16];
        #pragma unroll
        for (int id = 0; id < 16; id++) {
            qre[id] = fmaf(C7f, are[id], fmaf(C8f, a2re[id], cre[id]));
            qim[id] = fmaf(C7f, aim[id], fmaf(C8f, a2im[id], cim[id]));
        }
        if (onDiag) { qre[0] += C6f; qre[5] += C6f; qre[10] += C6f; qre[15] += C6f; }
        writeXtile(X, ri, c1, c2, qre, qim);
    }
    __syncthreads();

    // ---- mm4: M4 = A3*Q2 ;  Q1 = c3 I + c4 A + c5 A2 + M4 -> X ----
    ZERO_C
    mm_step(X, Y, ri, ci, c1, c2, false, cre, cim);
    __syncthreads();
    {
        float qre[16], qim[16];
        #pragma unroll
        for (int id = 0; id < 16; id++) {
            qre[id] = fmaf(C4f, are[id], fmaf(C5f, a2re[id], cre[id]));
            qim[id] = fmaf(C4f, aim[id], fmaf(C5f, a2im[id], cim[id]));
        }
        if (onDiag) { qre[0] += C3f; qre[5] += C3f; qre[10] += C3f; qre[15] += C3f; }
        writeXtile(X, ri, c1, c2, qre, qim);
    }
    __syncthreads();

    // ---- mm5: M5 = A3*Q1 ;  U = I + A + A2/2 + M5 (registers) ----
    ZERO_C
    mm_step(X, Y, ri, ci, c1, c2, false, cre, cim);
    float ure[16], uim[16];
    #pragma unroll
    for (int id = 0; id < 16; id++) {
        ure[id] = fmaf(0.5f, a2re[id], are[id] + cre[id]);
        uim[id] = fmaf(0.5f, a2im[id], aim[id] + cim[id]);
    }
    if (onDiag) { ure[0] += 1.f; ure[5] += 1.f; ure[10] += 1.f; ure[15] += 1.f; }
    __syncthreads();

    // ---- s squarings: U <- U*U ----
    for (int q = 0; q < s; q++) {
        writeYT(Y, ri, ci, ure, uim);        // Y <- U^T
        __syncthreads();
        ZERO_C
        mm_step(X, Y, ri, ci, c1, c2, true, cre, cim);
        __syncthreads();
        #pragma unroll
        for (int id = 0; id < 16; id++) { ure[id] = cre[id]; uim[id] = cim[id]; }
    }

    // ---- X <- U (plain-swizzled) ----
    writeXtile(X, ri, c1, c2, ure, uim);
    __syncthreads();
    #undef ZERO_C
}

// Pauli index p -> (xmask, zmask)
__device__ __forceinline__ void pauli_masks(int p, int& xm, int& zm) {
    xm = 0; zm = 0;
    #pragma unroll
    for (int k = 0; k < 6; k++) {
        int lo = (p >> (2 * k)) & 1;
        int hi = (p >> (2 * k + 1)) & 1;
        zm |= hi << k;
        xm |= (hi ^ lo) << k;
    }
}

__device__ __forceinline__ cplx pauli_phase(float v, int xm, int zm) {
    int ny = __popc(xm & zm) & 3;
    if (ny == 0) return make_float2(v, 0.f);
    if (ny == 1) return make_float2(0.f, -v);
    if (ny == 2) return make_float2(-v, 0.f);
    return make_float2(0.f, v);
}

// acc = M[i][:] . pin ; M in plain-swizzled layout; chunk rotation spreads rows
__device__ __forceinline__ cplx matvec_row(const cplx* __restrict__ M,
                                           const cplx* __restrict__ pin, int i)
{
    float ax = 0.f, ay = 0.f;
    const float4* Mr = (const float4*)(M + (i << 6));
    #pragma unroll
    for (int mm = 0; mm < 16; mm++) {
        int ch = (mm + (i & 15)) & 15;
        int b = (ch >> 2) & 1;
        float4 m01 = Mr[(ch << 1) + b];
        float4 m23 = Mr[(ch << 1) + 1 - b];
        const cplx* p = pin + (ch << 2);
        cplx p0 = p[0], p1 = p[1], p2 = p[2], p3 = p[3];
        ax = fmaf(m01.x, p0.x, fmaf(-m01.y, p0.y, ax));
        ay = fmaf(m01.x, p0.y, fmaf( m01.y, p0.x, ay));
        ax = fmaf(m01.z, p1.x, fmaf(-m01.w, p1.y, ax));
        ay = fmaf(m01.z, p1.y, fmaf( m01.w, p1.x, ay));
        ax = fmaf(m23.x, p2.x, fmaf(-m23.y, p2.y, ax));
        ay = fmaf(m23.x, p2.y, fmaf( m23.y, p2.x, ay));
        ax = fmaf(m23.z, p3.x, fmaf(-m23.w, p3.y, ax));
        ay = fmaf(m23.z, p3.y, fmaf( m23.w, p3.x, ay));
    }
    return make_float2(ax, ay);
}

// ---- parameter unitaries: Up[r] = exp(-i sum_p w[r,p-1] P_p) ----
__global__ __launch_bounds__(TPB) void up_kernel(const float* __restrict__ w,
                                                 cplx* __restrict__ up)
{
    __shared__ float4 Xs4[2048];
    __shared__ float4 Ys4[2048];
    cplx* X = (cplx*)Xs4;
    cplx* Y = (cplx*)Ys4;
    int t = threadIdx.x;
    int r = blockIdx.x;
    float sumsq = 0.f;
    #pragma unroll
    for (int n = 0; n < 16; n++) {
        int p = t + TPB * n;
        float v = (p == 0) ? 0.f : w[r * 4095 + p - 1];
        sumsq += v * v;
        int xm, zm; pauli_masks(p, xm, zm);
        X[(xm << 6) + zm] = pauli_phase(v, xm, zm);
    }
    __syncthreads();
    expm_core(X, Y, t, sumsq);
    // raw copy: `up` keeps the plain-swizzled layout (consumer is matvec_row)
    float4* dst = (float4*)(up + (r << 12));
    const float4* src = (const float4*)X;
    #pragma unroll
    for (int n = 0; n < 8; n++) dst[n * TPB + t] = src[n * TPB + t];
}

// ---- per-sample: Ud = exp(-iHd), circuit, probs + bias ----
__global__ __launch_bounds__(TPB) void circuit_kernel(const float* __restrict__ x,
                                                      const cplx* __restrict__ up,
                                                      const float* __restrict__ bias,
                                                      float* __restrict__ out)
{
    __shared__ float4 Xs4[2048];
    __shared__ float4 Ys4[2048];
    __shared__ cplx psiA[64], psiB[64];
    cplx* X = (cplx*)Xs4;
    cplx* Y = (cplx*)Ys4;
    int t = threadIdx.x;
    int b = blockIdx.x;
    float sumsq = 0.f;
    #pragma unroll
    for (int n = 0; n < 16; n++) {
        int p = t + TPB * n;
        float v = (p < IN_DIM) ? x[b * IN_DIM + p] : 0.f;
        sumsq += v * v;
        int xm, zm; pauli_masks(p, xm, zm);
        X[(xm << 6) + zm] = pauli_phase(v, xm, zm);
    }
    __syncthreads();
    expm_core(X, Y, t, sumsq);      // X = Ud (plain-swizzled); Y free

    if (t < 64) psiA[t] = make_float2(t == 0 ? 1.f : 0.f, 0.f);
    __syncthreads();

    for (int r = 0; r < NREPS; r++) {
        // stage Up[r] into Y (same swizzled layout), coalesced
        const float4* src = (const float4*)(up + (r << 12));
        float4* dstY = (float4*)Y;
        #pragma unroll
        for (int n = 0; n < 8; n++) dstY[n * TPB + t] = src[n * TPB + t];
        __syncthreads();
        if (t < 64) psiB[t] = matvec_row(X, psiA, t);
        __syncthreads();
        if (t < 64) psiA[t] = matvec_row(Y, psiB, t);
        __syncthreads();
    }
    if (t < 64) {
        cplx pv = psiA[t];
        out[(b << 6) + t] = fmaf(pv.x, pv.x, fmaf(pv.y, pv.y, bias[t]));
    }
}

extern "C" void kernel_launch(void* const* d_in, const int* in_sizes, int n_in,
                              void* d_out, int out_size, void* d_ws, size_t ws_size,
                              hipStream_t stream)
{
    const float* x    = (const float*)d_in[0];
    const float* w    = (const float*)d_in[1];
    const float* bias = (const float*)d_in[2];
    float* out = (float*)d_out;
    cplx* up   = (cplx*)d_ws;               // 4 * 4096 cplx = 128 KB scratch

    int B = in_sizes[0] / IN_DIM;           // 512

    hipLaunchKernelGGL(up_kernel,      dim3(NREPS), dim3(TPB), 0, stream, w, up);
    hipLaunchKernelGGL(circuit_kernel, dim3(B),     dim3(TPB), 0, stream, x, up, bias, out);
}